// Round 4
// baseline (1253.488 us; speedup 1.0000x reference)
//
#include <hip/hip_runtime.h>
#include <hip/hip_bf16.h>
#include <stdint.h>
#include <stddef.h>

using bf16  = __hip_bfloat16;
using v4s   = __attribute__((ext_vector_type(4))) short;
using v8s   = __attribute__((ext_vector_type(8))) short;
using f32x4 = __attribute__((ext_vector_type(4))) float;

#define MFMA_16x16x32(a, b, c) __builtin_amdgcn_mfma_f32_16x16x32_bf16((a), (b), (c), 0, 0, 0)

// TBAA-safe bf16 bit pattern as short (memcpy folds to a bit-cast).
__device__ __forceinline__ short bf16_bits(float f) {
  bf16 h = __float2bfloat16(f);
  short s;
  __builtin_memcpy(&s, &h, sizeof(s));
  return s;
}

// ---------------------------------------------------------------------------
// fp32 -> bf16 conversion (RNE), 4 elements/thread via float4.
// ---------------------------------------------------------------------------
__global__ void cvt_f32_bf16(const float* __restrict__ in, bf16* __restrict__ out,
                             int n4) {
  const int i = blockIdx.x * blockDim.x + threadIdx.x;
  if (i >= n4) return;
  const float4 f = ((const float4*)in)[i];
  v4s o;
  o[0] = bf16_bits(f.x);
  o[1] = bf16_bits(f.y);
  o[2] = bf16_bits(f.z);
  o[3] = bf16_bits(f.w);
  *(v4s*)(out + (size_t)i * 4) = o;
}

// ---------------------------------------------------------------------------
// GEMM: C[M,N] = A[M,K] @ B[N,K]^T, bf16 in, fp32 accum, bf16 or fp32 out.
// 128x128 tile, BK=32, 4 waves (2x2 of 64x64). Staging: global v8s load ->
// ds_write_b128 into frag-ordered LDS (lane-sequential, conflict-free
// ds_read_b128 on the way out). v8s on BOTH sides of the barrier (same TBAA).
// ---------------------------------------------------------------------------
template <bool F32OUT>
__global__ __launch_bounds__(256) void gemm_bt(const bf16* __restrict__ A,
                                               const bf16* __restrict__ B,
                                               void* __restrict__ C,
                                               int M, int N, int K) {
  __shared__ bf16 As[8 * 512];
  __shared__ bf16 Bs[8 * 512];
  const int tid  = threadIdx.x;
  const int w    = tid >> 6;
  const int lane = tid & 63;
  const int quad = lane >> 4;
  const int m16  = lane & 15;
  const int tm = blockIdx.y, tn = blockIdx.x;
  const int wrow = w >> 1, wcol = w & 1;

  f32x4 acc[4][4] = {};

  const bf16* Ag0 = A + (size_t)(tm * 128 + (w * 2 + 0) * 16 + m16) * K + quad * 8;
  const bf16* Ag1 = A + (size_t)(tm * 128 + (w * 2 + 1) * 16 + m16) * K + quad * 8;
  const bf16* Bg0 = B + (size_t)(tn * 128 + (w * 2 + 0) * 16 + m16) * K + quad * 8;
  const bf16* Bg1 = B + (size_t)(tn * 128 + (w * 2 + 1) * 16 + m16) * K + quad * 8;
  bf16* As0 = &As[(w * 2 + 0) * 512 + lane * 8];
  bf16* As1 = &As[(w * 2 + 1) * 512 + lane * 8];
  bf16* Bs0 = &Bs[(w * 2 + 0) * 512 + lane * 8];
  bf16* Bs1 = &Bs[(w * 2 + 1) * 512 + lane * 8];

  for (int k0 = 0; k0 < K; k0 += 32) {
    v8s a0 = *(const v8s*)(Ag0 + k0);
    v8s a1 = *(const v8s*)(Ag1 + k0);
    v8s b0 = *(const v8s*)(Bg0 + k0);
    v8s b1 = *(const v8s*)(Bg1 + k0);
    *(v8s*)As0 = a0;
    *(v8s*)As1 = a1;
    *(v8s*)Bs0 = b0;
    *(v8s*)Bs1 = b1;
    __syncthreads();
    v8s af[4], bfv[4];
#pragma unroll
    for (int i = 0; i < 4; ++i) af[i]  = *(const v8s*)&As[(wrow * 4 + i) * 512 + lane * 8];
#pragma unroll
    for (int i = 0; i < 4; ++i) bfv[i] = *(const v8s*)&Bs[(wcol * 4 + i) * 512 + lane * 8];
#pragma unroll
    for (int mi = 0; mi < 4; ++mi)
#pragma unroll
      for (int ni = 0; ni < 4; ++ni)
        acc[mi][ni] = MFMA_16x16x32(af[mi], bfv[ni], acc[mi][ni]);
    __syncthreads();
  }
#pragma unroll
  for (int mi = 0; mi < 4; ++mi)
#pragma unroll
    for (int ni = 0; ni < 4; ++ni) {
      const int row = tm * 128 + wrow * 64 + mi * 16 + quad * 4;
      const int col = tn * 128 + wcol * 64 + ni * 16 + m16;
#pragma unroll
      for (int r = 0; r < 4; ++r) {
        if (F32OUT)
          ((float*)C)[(size_t)(row + r) * N + col] = acc[mi][ni][r];
        else
          ((bf16*)C)[(size_t)(row + r) * N + col] = __float2bfloat16(acc[mi][ni][r]);
      }
    }
}

// ---------------------------------------------------------------------------
// RoPE, IN PLACE: rotate pairs (d, d+64) within each head; cos/sin in fp32
// (reference tables are fp32). One block = one (t, head).
// grid = (T, 40): blockIdx.y < 32 -> q head, else k head. block = 128 (=D).
// ---------------------------------------------------------------------------
__global__ void rope_kernel(bf16* __restrict__ q, bf16* __restrict__ k) {
  const int t  = blockIdx.x;
  const int hh = blockIdx.y;
  const int d  = threadIdx.x;  // 0..127
  const float invf = powf(10000.0f, -(float)(d & 63) * (1.0f / 64.0f));
  const float ang  = (float)t * invf;
  const float c = cosf(ang);
  const float s = sinf(ang);
  bf16* ptr = (hh < 32) ? (q + (size_t)t * 4096 + hh * 128)
                        : (k + (size_t)t * 1024 + (hh - 32) * 128);
  const float x   = __bfloat162float(ptr[d]);
  const float xp  = __bfloat162float(ptr[d ^ 64]);
  __syncthreads();
  const float rot = (d < 64) ? -xp : xp;
  ptr[d] = __float2bfloat16(x * c + rot * s);
}

// ---------------------------------------------------------------------------
// V transpose: v[T][1024] -> vT[1024][T]  (so PV B-frags read 8 contiguous t).
// ---------------------------------------------------------------------------
__global__ void vtrans_kernel(const bf16* __restrict__ v, bf16* __restrict__ vt) {
  __shared__ bf16 tile[32][34];
  const int t0 = blockIdx.x * 32, c0 = blockIdx.y * 32;
  const int tx = threadIdx.x, ty = threadIdx.y;  // 32, 8
#pragma unroll
  for (int i = 0; i < 4; ++i)
    tile[ty + 8 * i][tx] = v[(size_t)(t0 + ty + 8 * i) * 1024 + c0 + tx];
  __syncthreads();
#pragma unroll
  for (int i = 0; i < 4; ++i)
    vt[(size_t)(c0 + ty + 8 * i) * 2048 + t0 + tx] = tile[tx][ty + 8 * i];
}

// ---------------------------------------------------------------------------
// Fused causal flash attention, one block per (q-tile of 128, head).
// 4 waves; wave owns 32 q rows (2 m-tiles). Q A-frags preloaded in registers.
// K / V^T B-frags loaded straight from global (L2-resident). P round-trips
// through LDS in A-frag order (short on both sides; __syncthreads fenced).
// O is written IN PLACE over Q (block (qt,h) is the only reader of its own
// Q slice and holds it in registers before any store).
// ---------------------------------------------------------------------------
__global__ __launch_bounds__(256) void attn_fused(const bf16* __restrict__ Kc,
                                                  const bf16* __restrict__ Vt,
                                                  bf16* __restrict__ QO) {
  const int qt = blockIdx.x, h = blockIdx.y, hk = h >> 2;
  const int tid = threadIdx.x, w = tid >> 6, lane = tid & 63;
  const int quad = lane >> 4, m16 = lane & 15;
  __shared__ short Pl[4 * 2 * 4 * 512];  // [wave][mi][kp][frag elems]
  const float scale = 0.08838834764831845f;  // 1/sqrt(128)

  v8s qf[2][4];
#pragma unroll
  for (int mi = 0; mi < 2; ++mi) {
    const int row = qt * 128 + w * 32 + mi * 16 + m16;
#pragma unroll
    for (int ks = 0; ks < 4; ++ks)
      qf[mi][ks] = *(const v8s*)(QO + (size_t)row * 4096 + h * 128 + ks * 32 + quad * 8);
  }

  f32x4 acc[2][8] = {};
  float m_run[2][4], l_run[2][4];
#pragma unroll
  for (int mi = 0; mi < 2; ++mi)
#pragma unroll
    for (int r = 0; r < 4; ++r) { m_run[mi][r] = -1e30f; l_run[mi][r] = 0.f; }

  for (int kt = 0; kt <= qt; ++kt) {
    // S = Q K^T for this 128x128 tile (per wave: 32x128)
    f32x4 s[2][8] = {};
#pragma unroll
    for (int ni = 0; ni < 8; ++ni) {
      const bf16* kptr = Kc + (size_t)(kt * 128 + ni * 16 + m16) * 1024 + hk * 128 + quad * 8;
#pragma unroll
      for (int ks = 0; ks < 4; ++ks) {
        v8s kf = *(const v8s*)(kptr + ks * 32);
        s[0][ni] = MFMA_16x16x32(qf[0][ks], kf, s[0][ni]);
        s[1][ni] = MFMA_16x16x32(qf[1][ks], kf, s[1][ni]);
      }
    }
    // online softmax per m-tile
#pragma unroll
    for (int mi = 0; mi < 2; ++mi) {
      const int rowb = qt * 128 + w * 32 + mi * 16 + quad * 4;
      float mx[4] = {-1e30f, -1e30f, -1e30f, -1e30f};
#pragma unroll
      for (int ni = 0; ni < 8; ++ni) {
        const int col = kt * 128 + ni * 16 + m16;
#pragma unroll
        for (int r = 0; r < 4; ++r) {
          float v = s[mi][ni][r] * scale;
          if (col > rowb + r) v = -1e30f;  // causal (only bites when kt==qt)
          s[mi][ni][r] = v;
          mx[r] = fmaxf(mx[r], v);
        }
      }
#pragma unroll
      for (int off = 8; off >= 1; off >>= 1)
#pragma unroll
        for (int r = 0; r < 4; ++r)
          mx[r] = fmaxf(mx[r], __shfl_xor(mx[r], off));
      float al[4], rs[4] = {0.f, 0.f, 0.f, 0.f};
#pragma unroll
      for (int r = 0; r < 4; ++r) {
        const float nm = fmaxf(m_run[mi][r], mx[r]);
        al[r] = __expf(m_run[mi][r] - nm);
        m_run[mi][r] = nm;
      }
#pragma unroll
      for (int ni = 0; ni < 8; ++ni)
#pragma unroll
        for (int r = 0; r < 4; ++r) {
          const float p = __expf(s[mi][ni][r] - m_run[mi][r]);
          s[mi][ni][r] = p;
          rs[r] += p;
        }
#pragma unroll
      for (int off = 8; off >= 1; off >>= 1)
#pragma unroll
        for (int r = 0; r < 4; ++r)
          rs[r] += __shfl_xor(rs[r], off);
#pragma unroll
      for (int r = 0; r < 4; ++r)
        l_run[mi][r] = l_run[mi][r] * al[r] + rs[r];
#pragma unroll
      for (int nd = 0; nd < 8; ++nd)
#pragma unroll
        for (int r = 0; r < 4; ++r)
          acc[mi][nd][r] *= al[r];
      // write P (C-layout) into A-frag-ordered LDS block for this (wave, mi)
#pragma unroll
      for (int ni = 0; ni < 8; ++ni) {
        const int base = ((w * 2 + mi) * 4 + (ni >> 1)) * 512 +
                         ((ni & 1) * 2 + (m16 >> 3)) * 128 + quad * 32 + (m16 & 7);
#pragma unroll
        for (int r = 0; r < 4; ++r)
          Pl[base + r * 8] = bf16_bits(s[mi][ni][r]);
      }
    }
    __syncthreads();  // P writes -> P frag reads
    // O += P V   (P A-frags from LDS, V^T B-frags from global)
#pragma unroll
    for (int kp2 = 0; kp2 < 4; ++kp2) {
      v8s pf0 = *(const v8s*)&Pl[((w * 2 + 0) * 4 + kp2) * 512 + lane * 8];
      v8s pf1 = *(const v8s*)&Pl[((w * 2 + 1) * 4 + kp2) * 512 + lane * 8];
      const bf16* vptr = Vt + (size_t)(hk * 128 + m16) * 2048 + kt * 128 + kp2 * 32 + quad * 8;
#pragma unroll
      for (int nd = 0; nd < 8; ++nd) {
        v8s vf = *(const v8s*)(vptr + (size_t)nd * 16 * 2048);
        acc[0][nd] = MFMA_16x16x32(pf0, vf, acc[0][nd]);
        acc[1][nd] = MFMA_16x16x32(pf1, vf, acc[1][nd]);
      }
    }
    __syncthreads();  // P frag reads -> next iteration's P writes
  }
  // epilogue: normalize and store [t][h*128+d] bf16, in place over Q
#pragma unroll
  for (int mi = 0; mi < 2; ++mi)
#pragma unroll
    for (int nd = 0; nd < 8; ++nd) {
      const int row = qt * 128 + w * 32 + mi * 16 + quad * 4;
      const int col = h * 128 + nd * 16 + m16;
#pragma unroll
      for (int r = 0; r < 4; ++r)
        QO[(size_t)(row + r) * 4096 + col] = __float2bfloat16(acc[mi][nd][r] / l_run[mi][r]);
    }
}

// ---------------------------------------------------------------------------
extern "C" void kernel_launch(void* const* d_in, const int* in_sizes, int n_in,
                              void* d_out, int out_size, void* d_ws, size_t ws_size,
                              hipStream_t stream) {
  const float* stm = (const float*)d_in[0];  // [2048][4096] fp32
  const float* w_q = (const float*)d_in[1];  // [4096][4096] fp32
  const float* w_k = (const float*)d_in[2];  // [1024][4096] fp32
  const float* w_v = (const float*)d_in[3];  // [1024][4096] fp32
  const float* w_o = (const float*)d_in[4];  // [4096][4096] fp32
  float* out = (float*)d_out;                // [2048][4096] fp32

  const size_t M_STM = (size_t)2048 * 4096;  //  8M
  const size_t M_WQ  = (size_t)4096 * 4096;  // 16M
  const size_t M_WK  = (size_t)1024 * 4096;  //  4M

  bf16* ws     = (bf16*)d_ws;
  bf16* stm_bf = ws;                   // 8M   } region A (16M), later wo_bf
  bf16* wk_bf  = stm_bf + M_STM;       // 4M   }
  bf16* wv_bf  = wk_bf + M_WK;         // 4M   }
  bf16* wo_bf  = ws;                   // 16M  (overlays region A after QKV gemms)
  bf16* wq_bf  = ws + 16 * 1024 * 1024;       // 16M
  bf16* q_buf  = wq_bf + M_WQ;                // 8M  (q, then attn output)
  bf16* k_buf  = q_buf + M_STM;               // 2M
  bf16* v_buf  = k_buf + (size_t)2048 * 1024; // 2M
  bf16* vT     = v_buf + (size_t)2048 * 1024; // 2M
  // total: 46M bf16 = 92 MB

  cvt_f32_bf16<<<(int)(M_STM / 4 / 256), 256, 0, stream>>>(stm, stm_bf, (int)(M_STM / 4));
  cvt_f32_bf16<<<(int)(M_WQ / 4 / 256), 256, 0, stream>>>(w_q, wq_bf, (int)(M_WQ / 4));
  cvt_f32_bf16<<<(int)(M_WK / 4 / 256), 256, 0, stream>>>(w_k, wk_bf, (int)(M_WK / 4));
  cvt_f32_bf16<<<(int)(M_WK / 4 / 256), 256, 0, stream>>>(w_v, wv_bf, (int)(M_WK / 4));

  gemm_bt<false><<<dim3(32, 16), 256, 0, stream>>>(stm_bf, wq_bf, q_buf, 2048, 4096, 4096);
  gemm_bt<false><<<dim3(8, 16), 256, 0, stream>>>(stm_bf, wk_bf, k_buf, 2048, 1024, 4096);
  gemm_bt<false><<<dim3(8, 16), 256, 0, stream>>>(stm_bf, wv_bf, v_buf, 2048, 1024, 4096);
  rope_kernel<<<dim3(2048, 40), 128, 0, stream>>>(q_buf, k_buf);
  vtrans_kernel<<<dim3(64, 32), dim3(32, 8), 0, stream>>>(v_buf, vT);
  attn_fused<<<dim3(16, 32), 256, 0, stream>>>(k_buf, vT, q_buf);
  cvt_f32_bf16<<<(int)(M_WQ / 4 / 256), 256, 0, stream>>>(w_o, wo_bf, (int)(M_WQ / 4));
  gemm_bt<true><<<dim3(32, 16), 256, 0, stream>>>(q_buf, wo_bf, out, 2048, 4096, 4096);
}

// Round 5
// 1130.909 us; speedup vs baseline: 1.1084x; 1.1084x over previous
//
#include <hip/hip_runtime.h>
#include <hip/hip_bf16.h>
#include <stdint.h>
#include <stddef.h>

using bf16  = __hip_bfloat16;
using v4s   = __attribute__((ext_vector_type(4))) short;
using v8s   = __attribute__((ext_vector_type(8))) short;
using f32x4 = __attribute__((ext_vector_type(4))) float;
using i32x4 = __attribute__((ext_vector_type(4))) int;

#define MFMA_16x16x32(a, b, c) __builtin_amdgcn_mfma_f32_16x16x32_bf16((a), (b), (c), 0, 0, 0)

// TBAA-safe bf16 bit pattern as short (memcpy folds to a bit-cast).
__device__ __forceinline__ short bf16_bits(float f) {
  bf16 h = __float2bfloat16(f);
  short s;
  __builtin_memcpy(&s, &h, sizeof(s));
  return s;
}

// pack two fp32 -> bf16x2 in one dword (low short = x)
__device__ __forceinline__ int pack_bf16x2(float x, float y) {
  return (int)(unsigned short)bf16_bits(x) | ((int)bf16_bits(y) << 16);
}

// ---------------------------------------------------------------------------
// fp32 -> bf16 conversion (RNE), 4 elements/thread via float4.
// ---------------------------------------------------------------------------
__global__ void cvt_f32_bf16(const float* __restrict__ in, bf16* __restrict__ out,
                             int n4) {
  const int i = blockIdx.x * blockDim.x + threadIdx.x;
  if (i >= n4) return;
  const float4 f = ((const float4*)in)[i];
  v4s o;
  o[0] = bf16_bits(f.x);
  o[1] = bf16_bits(f.y);
  o[2] = bf16_bits(f.z);
  o[3] = bf16_bits(f.w);
  *(v4s*)(out + (size_t)i * 4) = o;
}

// ---------------------------------------------------------------------------
// GEMM: C[M,N] = A[M,K] @ B[N,K]^T, bf16 in, fp32 accum, bf16 or fp32 out.
// 128x128 tile, BK=32, 4 waves (2x2 of 64x64). Frag-ordered LDS staging.
// ---------------------------------------------------------------------------
template <bool F32OUT>
__global__ __launch_bounds__(256) void gemm_bt(const bf16* __restrict__ A,
                                               const bf16* __restrict__ B,
                                               void* __restrict__ C,
                                               int M, int N, int K) {
  __shared__ bf16 As[8 * 512];
  __shared__ bf16 Bs[8 * 512];
  const int tid  = threadIdx.x;
  const int w    = tid >> 6;
  const int lane = tid & 63;
  const int quad = lane >> 4;
  const int m16  = lane & 15;
  const int tm = blockIdx.y, tn = blockIdx.x;
  const int wrow = w >> 1, wcol = w & 1;

  f32x4 acc[4][4] = {};

  const bf16* Ag0 = A + (size_t)(tm * 128 + (w * 2 + 0) * 16 + m16) * K + quad * 8;
  const bf16* Ag1 = A + (size_t)(tm * 128 + (w * 2 + 1) * 16 + m16) * K + quad * 8;
  const bf16* Bg0 = B + (size_t)(tn * 128 + (w * 2 + 0) * 16 + m16) * K + quad * 8;
  const bf16* Bg1 = B + (size_t)(tn * 128 + (w * 2 + 1) * 16 + m16) * K + quad * 8;
  bf16* As0 = &As[(w * 2 + 0) * 512 + lane * 8];
  bf16* As1 = &As[(w * 2 + 1) * 512 + lane * 8];
  bf16* Bs0 = &Bs[(w * 2 + 0) * 512 + lane * 8];
  bf16* Bs1 = &Bs[(w * 2 + 1) * 512 + lane * 8];

  for (int k0 = 0; k0 < K; k0 += 32) {
    v8s a0 = *(const v8s*)(Ag0 + k0);
    v8s a1 = *(const v8s*)(Ag1 + k0);
    v8s b0 = *(const v8s*)(Bg0 + k0);
    v8s b1 = *(const v8s*)(Bg1 + k0);
    *(v8s*)As0 = a0;
    *(v8s*)As1 = a1;
    *(v8s*)Bs0 = b0;
    *(v8s*)Bs1 = b1;
    __syncthreads();
    v8s af[4], bfv[4];
#pragma unroll
    for (int i = 0; i < 4; ++i) af[i]  = *(const v8s*)&As[(wrow * 4 + i) * 512 + lane * 8];
#pragma unroll
    for (int i = 0; i < 4; ++i) bfv[i] = *(const v8s*)&Bs[(wcol * 4 + i) * 512 + lane * 8];
#pragma unroll
    for (int mi = 0; mi < 4; ++mi)
#pragma unroll
      for (int ni = 0; ni < 4; ++ni)
        acc[mi][ni] = MFMA_16x16x32(af[mi], bfv[ni], acc[mi][ni]);
    __syncthreads();
  }
#pragma unroll
  for (int mi = 0; mi < 4; ++mi)
#pragma unroll
    for (int ni = 0; ni < 4; ++ni) {
      const int row = tm * 128 + wrow * 64 + mi * 16 + quad * 4;
      const int col = tn * 128 + wcol * 64 + ni * 16 + m16;
#pragma unroll
      for (int r = 0; r < 4; ++r) {
        if (F32OUT)
          ((float*)C)[(size_t)(row + r) * N + col] = acc[mi][ni][r];
        else
          ((bf16*)C)[(size_t)(row + r) * N + col] = __float2bfloat16(acc[mi][ni][r]);
      }
    }
}

// ---------------------------------------------------------------------------
// RoPE, IN PLACE on qkv[t][6144]: q cols [h*128), k cols 4096+[hk*128).
// Scale 1/sqrt(128) folded into q (linear op commutes with rotation).
// grid = (T, 40): blockIdx.y < 32 -> q head, else k head. block = 128 (=D).
// ---------------------------------------------------------------------------
__global__ void rope_kernel(bf16* __restrict__ qkv) {
  const int t  = blockIdx.x;
  const int hh = blockIdx.y;
  const int d  = threadIdx.x;  // 0..127
  const float invf = powf(10000.0f, -(float)(d & 63) * (1.0f / 64.0f));
  const float ang  = (float)t * invf;
  const float c = cosf(ang);
  const float s = sinf(ang);
  const bool isq = (hh < 32);
  bf16* ptr = qkv + (size_t)t * 6144 + (isq ? hh * 128 : 4096 + (hh - 32) * 128);
  const float x   = __bfloat162float(ptr[d]);
  const float xp  = __bfloat162float(ptr[d ^ 64]);
  __syncthreads();
  const float rot = (d < 64) ? -xp : xp;
  const float outv = (x * c + rot * s) * (isq ? 0.08838834764831845f : 1.0f);
  ptr[d] = __float2bfloat16(outv);
}

// ---------------------------------------------------------------------------
// V transpose: qkv[t][5120 + c] -> vT[c][t]  (c in [0,1024), stride-2048 out).
// ---------------------------------------------------------------------------
__global__ void vtrans_kernel(const bf16* __restrict__ qkv, bf16* __restrict__ vt) {
  __shared__ bf16 tile[32][34];
  const int t0 = blockIdx.x * 32, c0 = blockIdx.y * 32;
  const int tx = threadIdx.x, ty = threadIdx.y;  // 32, 8
#pragma unroll
  for (int i = 0; i < 4; ++i)
    tile[ty + 8 * i][tx] = qkv[(size_t)(t0 + ty + 8 * i) * 6144 + 5120 + c0 + tx];
  __syncthreads();
#pragma unroll
  for (int i = 0; i < 4; ++i)
    vt[(size_t)(c0 + ty + 8 * i) * 2048 + t0 + tx] = tile[tx][ty + 8 * i];
}

// ---------------------------------------------------------------------------
// Fused causal flash attention, S^T formulation.
// One block = (64 q-rows, head); 4 independent waves (16 q each); NO barriers.
// S^T = K·Q^T (A=K-frag, B=Q^T-frag) -> C-layout holds k consecutive per lane:
//   - softmax state m/l/alpha is a per-lane scalar (q = lane&15)
//   - k-reduction = in-lane + 2 shfl_xor (16, 32)
//   - P^T -> PV B-frag transform: per-wave LDS, b64 writes, b128 reads
// O^T = V^T·P^T accumulated in C-layout -> 4 consecutive d per lane -> 8B
// vectorized stores. Mask only on the diagonal kt tile. Heavy blocks first.
// ---------------------------------------------------------------------------
__global__ __launch_bounds__(256) void attn_fused2(const bf16* __restrict__ QKV,
                                                   const bf16* __restrict__ Vt,
                                                   bf16* __restrict__ O) {
  const int q64 = 31 - (int)blockIdx.x;  // heavy (large q64) blocks dispatch first
  const int h = blockIdx.y, hk = h >> 2;
  const int tid = threadIdx.x, w = tid >> 6, lane = tid & 63;
  const int quad = lane >> 4, m16 = lane & 15;
  __shared__ int Pl[4 * 1024];  // per-wave 1024 dwords (4 kp-frags of 256)
  int* Pw = &Pl[w * 1024];

  const int qrow = q64 * 64 + w * 16 + m16;  // this lane's q (n-dim of S^T)

  // Q^T B-frags (scale already folded in by rope)
  v8s qf[4];
#pragma unroll
  for (int dk = 0; dk < 4; ++dk)
    qf[dk] = *(const v8s*)(QKV + (size_t)qrow * 6144 + h * 128 + dk * 32 + quad * 8);

  f32x4 acc[8] = {};
  float m_run = -1e30f, l_run = 0.f;

  const int nkt = (q64 >> 1) + 1;
  const int qloc = (q64 & 1) * 64 + w * 16 + m16;  // q local to diagonal kt tile

  for (int kt = 0; kt < nkt; ++kt) {
    const bool diag = (kt == nkt - 1);
    // ---- S^T = K (A) * Q^T (B): 8 k-time tiles x 4 d-chunks ----
    f32x4 s[8] = {};
#pragma unroll
    for (int ni = 0; ni < 8; ++ni) {
      const bf16* kptr =
          QKV + (size_t)(kt * 128 + ni * 16 + m16) * 6144 + 4096 + hk * 128 + quad * 8;
#pragma unroll
      for (int dk = 0; dk < 4; ++dk) {
        v8s kf = *(const v8s*)(kptr + dk * 32);
        s[ni] = MFMA_16x16x32(kf, qf[dk], s[ni]);
      }
    }
    if (diag) {
#pragma unroll
      for (int ni = 0; ni < 8; ++ni)
#pragma unroll
        for (int r = 0; r < 4; ++r)
          if (ni * 16 + quad * 4 + r > qloc) s[ni][r] = -1e30f;
    }
    // ---- online softmax over k (per-lane scalar state for q = m16) ----
    float mx = -1e30f;
#pragma unroll
    for (int ni = 0; ni < 8; ++ni)
#pragma unroll
      for (int r = 0; r < 4; ++r) mx = fmaxf(mx, s[ni][r]);
    mx = fmaxf(mx, __shfl_xor(mx, 16));
    mx = fmaxf(mx, __shfl_xor(mx, 32));
    const float mnew = fmaxf(m_run, mx);
    const float alpha = __expf(m_run - mnew);
    m_run = mnew;
    float rs = 0.f;
#pragma unroll
    for (int ni = 0; ni < 8; ++ni)
#pragma unroll
      for (int r = 0; r < 4; ++r) {
        const float p = __expf(s[ni][r] - mnew);
        s[ni][r] = p;
        rs += p;
      }
    rs += __shfl_xor(rs, 16);
    rs += __shfl_xor(rs, 32);
    l_run = l_run * alpha + rs;
#pragma unroll
    for (int nd = 0; nd < 8; ++nd)
#pragma unroll
      for (int r = 0; r < 4; ++r) acc[nd][r] *= alpha;
    // ---- pack P^T into per-wave LDS in PV B-frag order (b64 writes) ----
#pragma unroll
    for (int ni = 0; ni < 8; ++ni) {
      const int idx = (ni >> 1) * 256 + ((ni & 1) * 2 + (quad >> 1)) * 64 +
                      m16 * 4 + (quad & 1) * 2;
      int2 dd;
      dd.x = pack_bf16x2(s[ni][0], s[ni][1]);
      dd.y = pack_bf16x2(s[ni][2], s[ni][3]);
      *(int2*)&Pw[idx] = dd;
    }
    asm volatile("" ::: "memory");  // order P writes before frag reads (same wave)
    // ---- O^T += V^T (A) * P^T (B) ----
#pragma unroll
    for (int kp = 0; kp < 4; ++kp) {
      i32x4 t4 = *(const i32x4*)&Pw[kp * 256 + lane * 4];
      v8s pf;
      __builtin_memcpy(&pf, &t4, sizeof(pf));
      const bf16* vptr =
          Vt + (size_t)(hk * 128 + m16) * 2048 + kt * 128 + kp * 32 + quad * 8;
#pragma unroll
      for (int nd = 0; nd < 8; ++nd) {
        v8s vf = *(const v8s*)(vptr + (size_t)nd * 16 * 2048);
        acc[nd] = MFMA_16x16x32(vf, pf, acc[nd]);
      }
    }
    asm volatile("" ::: "memory");  // frag reads before next iteration's writes
  }
  // ---- epilogue: O[q][h*128+d], 4 consecutive d per lane -> 8B stores ----
  const float rl = 1.0f / l_run;
#pragma unroll
  for (int nd = 0; nd < 8; ++nd) {
    v4s o4;
#pragma unroll
    for (int r = 0; r < 4; ++r) o4[r] = bf16_bits(acc[nd][r] * rl);
    *(v4s*)(O + (size_t)qrow * 4096 + h * 128 + nd * 16 + quad * 4) = o4;
  }
}

// ---------------------------------------------------------------------------
extern "C" void kernel_launch(void* const* d_in, const int* in_sizes, int n_in,
                              void* d_out, int out_size, void* d_ws, size_t ws_size,
                              hipStream_t stream) {
  const float* stm = (const float*)d_in[0];  // [2048][4096] fp32
  const float* w_q = (const float*)d_in[1];  // [4096][4096] fp32
  const float* w_k = (const float*)d_in[2];  // [1024][4096] fp32
  const float* w_v = (const float*)d_in[3];  // [1024][4096] fp32
  const float* w_o = (const float*)d_in[4];  // [4096][4096] fp32
  float* out = (float*)d_out;                // [2048][4096] fp32

  const size_t M_STM = (size_t)2048 * 4096;  //  8M
  const size_t M_WQ  = (size_t)4096 * 4096;  // 16M
  const size_t M_WK  = (size_t)1024 * 4096;  //  4M

  bf16* ws      = (bf16*)d_ws;
  // [0, 24M): wqkv (wq 16M | wk 4M | wv 4M); after QKV gemm: wo overlays [0,16M),
  //           vT overlays [16M, 18M)
  bf16* wqkv_bf = ws;
  bf16* wo_bf   = ws;
  bf16* vT      = ws + M_WQ;
  // [24M, 32M): stm_bf; after QKV gemm: o_buf
  bf16* stm_bf  = ws + 24 * 1024 * 1024;
  bf16* o_buf   = stm_bf;
  // [32M, ~44.6M): qkv_buf [2048][6144]
  bf16* qkv_buf = ws + 32 * 1024 * 1024;

  cvt_f32_bf16<<<(int)(M_STM / 1024), 256, 0, stream>>>(stm, stm_bf, (int)(M_STM / 4));
  cvt_f32_bf16<<<(int)(M_WQ / 1024), 256, 0, stream>>>(w_q, wqkv_bf, (int)(M_WQ / 4));
  cvt_f32_bf16<<<(int)(M_WK / 1024), 256, 0, stream>>>(w_k, wqkv_bf + M_WQ, (int)(M_WK / 4));
  cvt_f32_bf16<<<(int)(M_WK / 1024), 256, 0, stream>>>(w_v, wqkv_bf + M_WQ + M_WK, (int)(M_WK / 4));

  // fused QKV projection: [2048,4096] x [6144,4096]^T -> [2048,6144]
  gemm_bt<false><<<dim3(48, 16), 256, 0, stream>>>(stm_bf, wqkv_bf, qkv_buf, 2048, 6144, 4096);

  // wqkv dead; stage w_o into its region
  cvt_f32_bf16<<<(int)(M_WQ / 1024), 256, 0, stream>>>(w_o, wo_bf, (int)(M_WQ / 4));

  rope_kernel<<<dim3(2048, 40), 128, 0, stream>>>(qkv_buf);
  vtrans_kernel<<<dim3(64, 32), dim3(32, 8), 0, stream>>>(qkv_buf, vT);
  attn_fused2<<<dim3(32, 32), 256, 0, stream>>>(qkv_buf, vT, o_buf);

  // output projection: [2048,4096] x [4096,4096]^T -> fp32 out
  gemm_bt<true><<<dim3(32, 16), 256, 0, stream>>>(o_buf, wo_bf, out, 2048, 4096, 4096);
}

// Round 6
// 742.073 us; speedup vs baseline: 1.6892x; 1.5240x over previous
//
#include <hip/hip_runtime.h>
#include <hip/hip_bf16.h>
#include <stdint.h>
#include <stddef.h>

using bf16  = __hip_bfloat16;
using v4s   = __attribute__((ext_vector_type(4))) short;
using v8s   = __attribute__((ext_vector_type(8))) short;
using f32x4 = __attribute__((ext_vector_type(4))) float;

#define MFMA_16x16x32(a, b, c) __builtin_amdgcn_mfma_f32_16x16x32_bf16((a), (b), (c), 0, 0, 0)

// Async global->LDS DMA, 16B/lane. lds base must be wave-uniform; lane i's
// 16B lands at lds + i*16 (m97-verified pattern).
__device__ __forceinline__ void async_lds16(const bf16* g, bf16* l) {
  __builtin_amdgcn_global_load_lds(
      (const __attribute__((address_space(1))) void*)g,
      (__attribute__((address_space(3))) void*)l, 16, 0, 0);
}

// TBAA-safe bf16 bit pattern as short (memcpy folds to a bit-cast).
__device__ __forceinline__ short bf16_bits(float f) {
  bf16 h = __float2bfloat16(f);
  short s;
  __builtin_memcpy(&s, &h, sizeof(s));
  return s;
}

// ---------------------------------------------------------------------------
// fp32 -> bf16 conversion (RNE), 4 elements/thread via float4.
// ---------------------------------------------------------------------------
__global__ void cvt_f32_bf16(const float* __restrict__ in, bf16* __restrict__ out,
                             int n4) {
  const int i = blockIdx.x * blockDim.x + threadIdx.x;
  if (i >= n4) return;
  const float4 f = ((const float4*)in)[i];
  v4s o;
  o[0] = bf16_bits(f.x);
  o[1] = bf16_bits(f.y);
  o[2] = bf16_bits(f.z);
  o[3] = bf16_bits(f.w);
  *(v4s*)(out + (size_t)i * 4) = o;
}

// ---------------------------------------------------------------------------
// GEMM: C[M,N] = A[M,K] @ B[N,K]^T, bf16 in, fp32 accum, bf16 or fp32 out.
// 128x128 tile, BK=32, 4 waves (2x2 of 64x64). Staging via global_load_lds
// width=16 into frag-ordered LDS (lane-sequential -> conflict-free b128 reads).
// ---------------------------------------------------------------------------
template <bool F32OUT>
__global__ __launch_bounds__(256) void gemm_bt(const bf16* __restrict__ A,
                                               const bf16* __restrict__ B,
                                               void* __restrict__ C,
                                               int M, int N, int K) {
  __shared__ bf16 As[8 * 512];
  __shared__ bf16 Bs[8 * 512];
  const int tid  = threadIdx.x;
  const int w    = tid >> 6;
  const int lane = tid & 63;
  const int quad = lane >> 4;
  const int m16  = lane & 15;
  const int tm = blockIdx.y, tn = blockIdx.x;
  const int wrow = w >> 1, wcol = w & 1;

  f32x4 acc[4][4] = {};

  const bf16* Ag0 = A + (size_t)(tm * 128 + (w * 2 + 0) * 16 + m16) * K + quad * 8;
  const bf16* Ag1 = A + (size_t)(tm * 128 + (w * 2 + 1) * 16 + m16) * K + quad * 8;
  const bf16* Bg0 = B + (size_t)(tn * 128 + (w * 2 + 0) * 16 + m16) * K + quad * 8;
  const bf16* Bg1 = B + (size_t)(tn * 128 + (w * 2 + 1) * 16 + m16) * K + quad * 8;
  bf16* As0 = &As[(w * 2 + 0) * 512];
  bf16* As1 = &As[(w * 2 + 1) * 512];
  bf16* Bs0 = &Bs[(w * 2 + 0) * 512];
  bf16* Bs1 = &Bs[(w * 2 + 1) * 512];

  for (int k0 = 0; k0 < K; k0 += 32) {
    async_lds16(Ag0 + k0, As0);
    async_lds16(Ag1 + k0, As1);
    async_lds16(Bg0 + k0, Bs0);
    async_lds16(Bg1 + k0, Bs1);
    __syncthreads();
    v8s af[4], bfv[4];
#pragma unroll
    for (int i = 0; i < 4; ++i) af[i]  = *(const v8s*)&As[(wrow * 4 + i) * 512 + lane * 8];
#pragma unroll
    for (int i = 0; i < 4; ++i) bfv[i] = *(const v8s*)&Bs[(wcol * 4 + i) * 512 + lane * 8];
#pragma unroll
    for (int mi = 0; mi < 4; ++mi)
#pragma unroll
      for (int ni = 0; ni < 4; ++ni)
        acc[mi][ni] = MFMA_16x16x32(af[mi], bfv[ni], acc[mi][ni]);
    __syncthreads();
  }
#pragma unroll
  for (int mi = 0; mi < 4; ++mi)
#pragma unroll
    for (int ni = 0; ni < 4; ++ni) {
      const int row = tm * 128 + wrow * 64 + mi * 16 + quad * 4;
      const int col = tn * 128 + wcol * 64 + ni * 16 + m16;
#pragma unroll
      for (int r = 0; r < 4; ++r) {
        if (F32OUT)
          ((float*)C)[(size_t)(row + r) * N + col] = acc[mi][ni][r];
        else
          ((bf16*)C)[(size_t)(row + r) * N + col] = __float2bfloat16(acc[mi][ni][r]);
      }
    }
}

// ---------------------------------------------------------------------------
// RoPE, IN PLACE on qkv[t][6144]: q cols [h*128), k cols 4096+[hk*128).
// Scale 1/sqrt(128) folded into q. grid = (T, 40), block = 128 (=D).
// ---------------------------------------------------------------------------
__global__ void rope_kernel(bf16* __restrict__ qkv) {
  const int t  = blockIdx.x;
  const int hh = blockIdx.y;
  const int d  = threadIdx.x;  // 0..127
  const float invf = powf(10000.0f, -(float)(d & 63) * (1.0f / 64.0f));
  const float ang  = (float)t * invf;
  const float c = cosf(ang);
  const float s = sinf(ang);
  const bool isq = (hh < 32);
  bf16* ptr = qkv + (size_t)t * 6144 + (isq ? hh * 128 : 4096 + (hh - 32) * 128);
  const float x   = __bfloat162float(ptr[d]);
  const float xp  = __bfloat162float(ptr[d ^ 64]);
  __syncthreads();
  const float rot = (d < 64) ? -xp : xp;
  const float outv = (x * c + rot * s) * (isq ? 0.08838834764831845f : 1.0f);
  ptr[d] = __float2bfloat16(outv);
}

// ---------------------------------------------------------------------------
// V transpose: qkv[t][5120 + c] -> vT[c][t]  (c in [0,1024), stride-2048 out).
// ---------------------------------------------------------------------------
__global__ void vtrans_kernel(const bf16* __restrict__ qkv, bf16* __restrict__ vt) {
  __shared__ bf16 tile[32][34];
  const int t0 = blockIdx.x * 32, c0 = blockIdx.y * 32;
  const int tx = threadIdx.x, ty = threadIdx.y;  // 32, 8
#pragma unroll
  for (int i = 0; i < 4; ++i)
    tile[ty + 8 * i][tx] = qkv[(size_t)(t0 + ty + 8 * i) * 6144 + 5120 + c0 + tx];
  __syncthreads();
#pragma unroll
  for (int i = 0; i < 4; ++i)
    vt[(size_t)(c0 + ty + 8 * i) * 2048 + t0 + tx] = tile[tx][ty + 8 * i];
}

// ---------------------------------------------------------------------------
// Fused causal flash attention v3 — m97-GEMM-shaped.
// Block = (128 q, head); 4 waves, wave owns 32 q columns. S^T formulation
// (S^T = K·Q^T) so softmax state is a per-lane scalar per 16-q tile.
// Per kt tile: cooperative global_load_lds staging of K (32KB) and Vt (32KB)
// into frag-ordered LDS; S from LDS frags; P^T packed into the (dead) Ks
// region (per-wave 8KB) after a barrier; PV from LDS. 3 barriers/iter.
// O^T in C-layout -> 4 consecutive d per lane -> 8B stores.
// ---------------------------------------------------------------------------
__global__ __launch_bounds__(256) void attn_fused3(const bf16* __restrict__ QKV,
                                                   const bf16* __restrict__ Vt,
                                                   bf16* __restrict__ O) {
  const int qt = 15 - (int)blockIdx.x;  // heavy blocks dispatch first
  const int h = blockIdx.y, hk = h >> 2;
  const int tid = threadIdx.x, w = tid >> 6, lane = tid & 63;
  const int quad = lane >> 4, m16 = lane & 15;
  __shared__ bf16 Ks[32 * 512];  // 32KB K frags; P^T overlays after barrier
  __shared__ bf16 Vs[32 * 512];  // 32KB Vt frags
  short* Pw = (short*)Ks + w * 4096;  // per-wave 8KB P region

  // Q^T B-frags (scale folded in by rope); wave owns q cols w*32 + ni*16 + m16
  v8s qf[2][4];
#pragma unroll
  for (int ni = 0; ni < 2; ++ni)
#pragma unroll
    for (int dk = 0; dk < 4; ++dk)
      qf[ni][dk] = *(const v8s*)(QKV + (size_t)(qt * 128 + w * 32 + ni * 16 + m16) * 6144 +
                                 h * 128 + dk * 32 + quad * 8);

  f32x4 acc[8][2] = {};
  float m_run[2] = {-1e30f, -1e30f}, l_run[2] = {0.f, 0.f};

  for (int kt = 0; kt <= qt; ++kt) {
    __syncthreads();  // prior iteration's P reads done before Ks restage
    // ---- cooperative staging: K-tile and Vt-tile, frag-ordered ----
    const bf16* kg = QKV + (size_t)(kt * 128 + m16) * 6144 + 4096 + hk * 128 + w * 32 + quad * 8;
    const bf16* vg = Vt + (size_t)(hk * 128 + m16) * 2048 + kt * 128 + w * 32 + quad * 8;
#pragma unroll
    for (int mi = 0; mi < 8; ++mi) {
      async_lds16(kg + (size_t)mi * 16 * 6144, &Ks[(mi * 4 + w) * 512]);
      async_lds16(vg + (size_t)mi * 16 * 2048, &Vs[(mi * 4 + w) * 512]);
    }
    __syncthreads();
    // ---- S^T = K (A-frags from LDS) * Q^T (B-frags in regs) ----
    f32x4 s[8][2];
#pragma unroll
    for (int mi = 0; mi < 8; ++mi) {
      s[mi][0] = f32x4{0.f, 0.f, 0.f, 0.f};
      s[mi][1] = f32x4{0.f, 0.f, 0.f, 0.f};
#pragma unroll
      for (int dk = 0; dk < 4; ++dk) {
        v8s af = *(const v8s*)&Ks[(mi * 4 + dk) * 512 + lane * 8];
        s[mi][0] = MFMA_16x16x32(af, qf[0][dk], s[mi][0]);
        s[mi][1] = MFMA_16x16x32(af, qf[1][dk], s[mi][1]);
      }
    }
    if (kt == qt) {  // causal mask, diagonal tile only
#pragma unroll
      for (int mi = 0; mi < 8; ++mi)
#pragma unroll
        for (int ni = 0; ni < 2; ++ni)
#pragma unroll
          for (int r = 0; r < 4; ++r)
            if (mi * 16 + quad * 4 + r > w * 32 + ni * 16 + m16) s[mi][ni][r] = -1e30f;
    }
    // ---- online softmax over k (per-lane scalar state per ni) ----
#pragma unroll
    for (int ni = 0; ni < 2; ++ni) {
      float mx = -1e30f;
#pragma unroll
      for (int mi = 0; mi < 8; ++mi)
#pragma unroll
        for (int r = 0; r < 4; ++r) mx = fmaxf(mx, s[mi][ni][r]);
      mx = fmaxf(mx, __shfl_xor(mx, 16));
      mx = fmaxf(mx, __shfl_xor(mx, 32));
      const float mnew = fmaxf(m_run[ni], mx);
      const float alpha = __expf(m_run[ni] - mnew);
      m_run[ni] = mnew;
      float rs = 0.f;
#pragma unroll
      for (int mi = 0; mi < 8; ++mi)
#pragma unroll
        for (int r = 0; r < 4; ++r) {
          const float p = __expf(s[mi][ni][r] - mnew);
          s[mi][ni][r] = p;
          rs += p;
        }
      rs += __shfl_xor(rs, 16);
      rs += __shfl_xor(rs, 32);
      l_run[ni] = l_run[ni] * alpha + rs;
#pragma unroll
      for (int mi2 = 0; mi2 < 8; ++mi2)
#pragma unroll
        for (int r = 0; r < 4; ++r) acc[mi2][ni][r] *= alpha;
    }
    __syncthreads();  // all waves done reading Ks; safe to overlay P
    // ---- pack P^T into per-wave B-frag-ordered LDS (b64 writes) ----
#pragma unroll
    for (int mi = 0; mi < 8; ++mi)
#pragma unroll
      for (int ni = 0; ni < 2; ++ni) {
        v4s p4;
#pragma unroll
        for (int r = 0; r < 4; ++r) p4[r] = bf16_bits(s[mi][ni][r]);
        const int base = (ni * 4 + (mi >> 1)) * 512 +
                         ((mi & 1) * 2 + (quad >> 1)) * 128 + m16 * 8 + (quad & 1) * 4;
        *(v4s*)&Pw[base] = p4;
      }
    asm volatile("" ::: "memory");  // same-wave: P writes before P frag reads
    // ---- O^T += Vt (A-frags from LDS) * P^T (B-frags from LDS) ----
#pragma unroll
    for (int kp = 0; kp < 4; ++kp) {
      v8s pf0 = *(const v8s*)&Pw[(0 * 4 + kp) * 512 + lane * 8];
      v8s pf1 = *(const v8s*)&Pw[(1 * 4 + kp) * 512 + lane * 8];
#pragma unroll
      for (int mi2 = 0; mi2 < 8; ++mi2) {
        v8s vf = *(const v8s*)&Vs[(mi2 * 4 + kp) * 512 + lane * 8];
        acc[mi2][0] = MFMA_16x16x32(vf, pf0, acc[mi2][0]);
        acc[mi2][1] = MFMA_16x16x32(vf, pf1, acc[mi2][1]);
      }
    }
  }
  // ---- epilogue: O[q][h*128+d], 4 consecutive d per lane -> 8B stores ----
#pragma unroll
  for (int ni = 0; ni < 2; ++ni) {
    const float rl = 1.0f / l_run[ni];
    const size_t qrow = qt * 128 + w * 32 + ni * 16 + m16;
#pragma unroll
    for (int mi2 = 0; mi2 < 8; ++mi2) {
      v4s o4;
#pragma unroll
      for (int r = 0; r < 4; ++r) o4[r] = bf16_bits(acc[mi2][ni][r] * rl);
      *(v4s*)(O + qrow * 4096 + h * 128 + mi2 * 16 + quad * 4) = o4;
    }
  }
}

// ---------------------------------------------------------------------------
extern "C" void kernel_launch(void* const* d_in, const int* in_sizes, int n_in,
                              void* d_out, int out_size, void* d_ws, size_t ws_size,
                              hipStream_t stream) {
  const float* stm = (const float*)d_in[0];  // [2048][4096] fp32
  const float* w_q = (const float*)d_in[1];  // [4096][4096] fp32
  const float* w_k = (const float*)d_in[2];  // [1024][4096] fp32
  const float* w_v = (const float*)d_in[3];  // [1024][4096] fp32
  const float* w_o = (const float*)d_in[4];  // [4096][4096] fp32
  float* out = (float*)d_out;                // [2048][4096] fp32

  const size_t M_STM = (size_t)2048 * 4096;  //  8M
  const size_t M_WQ  = (size_t)4096 * 4096;  // 16M
  const size_t M_WK  = (size_t)1024 * 4096;  //  4M

  bf16* ws      = (bf16*)d_ws;
  // [0, 24M): wqkv (wq 16M | wk 4M | wv 4M); after QKV gemm: wo overlays [0,16M),
  //           vT overlays [16M, 18M)
  bf16* wqkv_bf = ws;
  bf16* wo_bf   = ws;
  bf16* vT      = ws + M_WQ;
  // [24M, 32M): stm_bf; after QKV gemm: o_buf
  bf16* stm_bf  = ws + 24 * 1024 * 1024;
  bf16* o_buf   = stm_bf;
  // [32M, ~44.6M): qkv_buf [2048][6144]
  bf16* qkv_buf = ws + 32 * 1024 * 1024;

  cvt_f32_bf16<<<(int)(M_STM / 1024), 256, 0, stream>>>(stm, stm_bf, (int)(M_STM / 4));
  cvt_f32_bf16<<<(int)(M_WQ / 1024), 256, 0, stream>>>(w_q, wqkv_bf, (int)(M_WQ / 4));
  cvt_f32_bf16<<<(int)(M_WK / 1024), 256, 0, stream>>>(w_k, wqkv_bf + M_WQ, (int)(M_WK / 4));
  cvt_f32_bf16<<<(int)(M_WK / 1024), 256, 0, stream>>>(w_v, wqkv_bf + M_WQ + M_WK, (int)(M_WK / 4));

  // fused QKV projection: [2048,4096] x [6144,4096]^T -> [2048,6144]
  gemm_bt<false><<<dim3(48, 16), 256, 0, stream>>>(stm_bf, wqkv_bf, qkv_buf, 2048, 6144, 4096);

  // wqkv dead; stage w_o into its region
  cvt_f32_bf16<<<(int)(M_WQ / 1024), 256, 0, stream>>>(w_o, wo_bf, (int)(M_WQ / 4));

  rope_kernel<<<dim3(2048, 40), 128, 0, stream>>>(qkv_buf);
  vtrans_kernel<<<dim3(64, 32), dim3(32, 8), 0, stream>>>(qkv_buf, vT);
  attn_fused3<<<dim3(16, 32), 256, 0, stream>>>(qkv_buf, vT, o_buf);

  // output projection: [2048,4096] x [4096,4096]^T -> fp32 out
  gemm_bt<true><<<dim3(32, 16), 256, 0, stream>>>(o_buf, wo_bf, out, 2048, 4096, 4096);
}